// Round 15
// baseline (137.713 us; speedup 1.0000x reference)
//
#include <hip/hip_runtime.h>

using bf16 = __bf16;
typedef __attribute__((ext_vector_type(8))) __bf16 bf16x8;
typedef __attribute__((ext_vector_type(4))) __bf16 bf16x4;
typedef __attribute__((ext_vector_type(4))) float f32x4;
typedef __attribute__((ext_vector_type(16))) float f32x16;
typedef __attribute__((ext_vector_type(4))) unsigned u32x4;
typedef __attribute__((ext_vector_type(2))) unsigned u32x2;

#define NB 8
#define CC 512
#define LL 2048
#define IC 256
#define NLTOT 16384
#define NSPLIT 4
#define BATCH_STRIDE 524288   // 2048*256 elements per batch for q/k/v blocked tensors

__device__ inline bf16 f2bf(float f) {
    unsigned u = __builtin_bit_cast(unsigned, f);
    unsigned r = (u + 0x7fff + ((u >> 16) & 1)) >> 16;
    return __builtin_bit_cast(bf16, (unsigned short)r);
}
__device__ inline unsigned packbf(float lo, float hi) {
    unsigned a = (unsigned)__builtin_bit_cast(unsigned short, f2bf(lo));
    unsigned b = (unsigned)__builtin_bit_cast(unsigned short, f2bf(hi));
    return (b << 16) | a;
}
// exchange: a[32..63] <-> b[0..31]  (pure VALU; distinct live operands -> distinct regs)
__device__ inline void plswap(unsigned& a, unsigned& b) {
    asm("v_permlane32_swap_b32 %0, %1" : "+v"(a), "+v"(b));
}

typedef const __attribute__((address_space(1))) void gas_void;
typedef __attribute__((address_space(3))) void las_void;

// ---------------- ws layout (bytes) ----------------
static constexpr size_t oScale = 0;                       // 8192 B
static constexpr size_t oWT    = 8192;                    // thetaT,phiT,gT,WwT bf16
static constexpr size_t oAn    = oWT + 4ull * 262144;     // 16 MB (reused: attn partials span An+Bn)
static constexpr size_t oBn    = oAn + 16777216ull;       // 16 MB
static constexpr size_t oQ     = oBn + 16777216ull;       // 8 MB (qB blocked)
static constexpr size_t oK     = oQ + 8388608ull;         // 8 MB (kB blocked)
static constexpr size_t oVT    = oK + 8388608ull;         // 8 MB (vB blocked)
static constexpr size_t oY     = oVT + 8388608ull;        // 8 MB
static constexpr size_t oProj  = oY + 8388608ull;         // reused: attn m/l only (512 KB)

// ---------------- weight prep + BN stats in one launch ----------------
__global__ __launch_bounds__(256) void prep_and_stats(
    const float* __restrict__ theta_w, const float* __restrict__ phi_w,
    const float* __restrict__ g_w, const float* __restrict__ W_w,
    const float* __restrict__ A, const float* __restrict__ B,
    const float* __restrict__ gamma, const float* __restrict__ beta,
    bf16* __restrict__ wts, float* __restrict__ scaleshift)
{
    int bidx = blockIdx.x;
    int t = threadIdx.x;
    if (bidx < 2048) {
        int idx = bidx * 256 + t;
        int which = idx >> 17;
        int o = idx & 131071;
        float v;
        if (which < 3) {
            const float* W = which == 0 ? theta_w : (which == 1 ? phi_w : g_w);
            int ic = o >> 9, cc = o & 511;
            v = W[cc * IC + ic];
        } else {
            int cc = o >> 8, ic = o & 255;
            v = W_w[ic * CC + cc];
        }
        wts[(size_t)which * 131072 + o] = f2bf(v);
        return;
    }
    int bid = bidx - 2048;
    int tensor = bid >> 9, c = bid & 511;
    const float* X = tensor ? B : A;
    float s = 0.f, sq = 0.f;
    for (int n = 0; n < NB; ++n) {
        const float* row = &X[((size_t)(n * CC + c)) << 11];
        for (int j = t * 4; j < LL; j += 1024) {
            float4 v = *(const float4*)&row[j];
            s += v.x + v.y + v.z + v.w;
            sq += v.x * v.x + v.y * v.y + v.z * v.z + v.w * v.w;
        }
    }
    __shared__ float rs[256], rq[256];
    rs[t] = s; rq[t] = sq;
    __syncthreads();
    for (int step = 128; step > 0; step >>= 1) {
        if (t < step) { rs[t] += rs[t + step]; rq[t] += rq[t + step]; }
        __syncthreads();
    }
    if (t == 0) {
        float mean = rs[0] * (1.f / 16384.f);
        float var = rq[0] * (1.f / 16384.f) - mean * mean;
        float rsq = rsqrtf(var + 1e-5f);
        float sc = gamma[c] * rsq;
        scaleshift[tensor * 1024 + c] = sc;
        scaleshift[tensor * 1024 + 512 + c] = beta[c] - mean * sc;
    }
}

// ---------------- BN apply + ReLU + transpose -> bf16 [N,L,C], both tensors ----------------
__global__ __launch_bounds__(256) void bn_apply_transpose(
    const float* __restrict__ A, const float* __restrict__ B,
    const float* __restrict__ scaleshift,
    bf16* __restrict__ OutA, bf16* __restrict__ OutB)
{
    int bidx = blockIdx.x;                  // 4096 = 2 tensors * 2048
    int tensor = bidx >> 11;
    bidx &= 2047;
    const float* X = tensor ? B : A;
    const float* scale = scaleshift + tensor * 1024;
    const float* shift = scale + 512;
    bf16* Out = tensor ? OutB : OutA;
    int lt = bidx & 31, ct = (bidx >> 5) & 7, n = bidx >> 8;
    int c0 = ct * 64, l0 = lt * 64;
    __shared__ float tile[64][65];
    int t = threadIdx.x;
    #pragma unroll
    for (int i = 0; i < 4; ++i) {
        int r = i * 16 + (t >> 4);
        int c4 = (t & 15) * 4;
        float s = scale[c0 + r], sh = shift[c0 + r];
        float4 v = *(const float4*)&X[(((size_t)n * CC + c0 + r) << 11) + l0 + c4];
        tile[r][c4 + 0] = fmaxf(v.x * s + sh, 0.f);
        tile[r][c4 + 1] = fmaxf(v.y * s + sh, 0.f);
        tile[r][c4 + 2] = fmaxf(v.z * s + sh, 0.f);
        tile[r][c4 + 3] = fmaxf(v.w * s + sh, 0.f);
    }
    __syncthreads();
    #pragma unroll
    for (int i = 0; i < 2; ++i) {
        int lr = i * 32 + (t >> 3);
        int c8 = (t & 7) * 8;
        bf16 tmp[8];
        #pragma unroll
        for (int e = 0; e < 8; ++e) tmp[e] = f2bf(tile[c8 + e][lr]);
        *(bf16x8*)&Out[(((size_t)(n << 11)) + l0 + lr) * CC + c0 + c8] = *(bf16x8*)tmp;
    }
}

// ---------------- fused QKV GEMM: global_load_lds staging + XOR-swizzled LDS ----------------
__global__ __launch_bounds__(256) void gemm_qkv(
    const bf16* __restrict__ An, const bf16* __restrict__ Bn,
    const bf16* __restrict__ wts,
    const float* __restrict__ theta_b, const float* __restrict__ phi_b,
    const float* __restrict__ g_b,
    bf16* __restrict__ qB, bf16* __restrict__ kB, bf16* __restrict__ vB)
{
    int bid = blockIdx.x;
    int which = bid >> 8;
    int sub = bid & 255;
    const bf16* A  = (which == 1) ? Bn : An;
    const bf16* BT = wts + (size_t)which * 131072;
    const float* bias = which == 0 ? theta_b : (which == 1 ? phi_b : g_b);
    bf16* dst = which == 0 ? qB : (which == 1 ? kB : vB);

    int tn = sub & 1, tm = sub >> 1;
    int m0 = tm * 128, n0 = tn * 128;
    __shared__ bf16 a_lds[128 * 64];
    __shared__ bf16 b_lds[128 * 64];
    int t = threadIdx.x;
    int l = t & 63, w = t >> 6;
    int wr = w >> 1, wc = w & 1;
    f32x4 acc[4][4] = {};
    for (int k0 = 0; k0 < CC; k0 += 64) {
        __syncthreads();
        #pragma unroll
        for (int i = 0; i < 4; ++i) {
            int G = t + i * 256;             // 0..1023: row=G>>3, gcol=G&7
            int row = G >> 3;
            int gsrc = (G & 7) ^ (row & 7);  // inverse-swizzled source granule
            __builtin_amdgcn_global_load_lds(
                (gas_void*)&A[(size_t)(m0 + row) * CC + k0 + gsrc * 8],
                (las_void*)&a_lds[G * 8], 16, 0, 0);
            __builtin_amdgcn_global_load_lds(
                (gas_void*)&BT[(size_t)(n0 + row) * CC + k0 + gsrc * 8],
                (las_void*)&b_lds[G * 8], 16, 0, 0);
        }
        __syncthreads();                     // implicit vmcnt(0) drains the DMA
        #pragma unroll
        for (int ks = 0; ks < 2; ++ks) {
            bf16x8 af[4], bfr[4];
            int gc = ks * 4 + (l >> 4);
            #pragma unroll
            for (int mi = 0; mi < 4; ++mi) {
                int r = wr * 64 + mi * 16 + (l & 15);
                af[mi] = *(const bf16x8*)&a_lds[(r * 8 + (gc ^ (r & 7))) * 8];
            }
            #pragma unroll
            for (int ni = 0; ni < 4; ++ni) {
                int r = wc * 64 + ni * 16 + (l & 15);
                bfr[ni] = *(const bf16x8*)&b_lds[(r * 8 + (gc ^ (r & 7))) * 8];
            }
            #pragma unroll
            for (int mi = 0; mi < 4; ++mi)
                #pragma unroll
                for (int ni = 0; ni < 4; ++ni)
                    acc[mi][ni] = __builtin_amdgcn_mfma_f32_16x16x32_bf16(af[mi], bfr[ni], acc[mi][ni], 0, 0, 0);
        }
    }
    #pragma unroll
    for (int mi = 0; mi < 4; ++mi)
        #pragma unroll
        for (int ni = 0; ni < 4; ++ni) {
            int col = n0 + wc * 64 + ni * 16 + (l & 15);
            float bv = bias[col];
            int row0 = m0 + wr * 64 + mi * 16 + (l >> 4) * 4;
            int nb = row0 >> 11;
            int li0 = row0 & 2047;
            size_t base = (size_t)nb * BATCH_STRIDE + (size_t)(li0 >> 5) * 8192;
            if (which < 2) {
                size_t a0 = base + (col >> 3) * 256 + (li0 & 31) * 8 + (col & 7);
                #pragma unroll
                for (int r = 0; r < 4; ++r)
                    dst[a0 + r * 8] = f2bf(acc[mi][ni][r] + bv);
            } else {
                bf16 tmp[4];
                #pragma unroll
                for (int r = 0; r < 4; ++r) tmp[r] = f2bf(acc[mi][ni][r] + bv);
                int kvin = li0 & 31;
                int grp = ((col >> 5) << 2) | ((kvin >> 4) << 1) | ((kvin >> 3) & 1);
                *(bf16x4*)&dst[base + grp * 256 + (col & 31) * 8 + (kvin & 7)] = *(bf16x4*)tmp;
            }
        }
}

// ---------------- W-projection GEMM (same staging) fused with residual epilogue ----------------
__global__ __launch_bounds__(256) void gemm_w_fused(
    const bf16* __restrict__ Ay, const bf16* __restrict__ BT,
    const float* __restrict__ bias, const float* __restrict__ Aorig,
    const float* __restrict__ scaleshift, float* __restrict__ Out)
{
    int bid = blockIdx.x;                  // 512 = 128 m-tiles * 4 n-tiles
    int tn = bid & 3, tm = bid >> 2;
    int m0 = tm * 128, n0 = tn * 128;
    __shared__ bf16 a_lds[128 * 64];
    __shared__ bf16 b_lds[128 * 64];
    int t = threadIdx.x;
    int l = t & 63, w = t >> 6;
    int wr = w >> 1, wc = w & 1;
    f32x4 acc[4][4] = {};
    for (int k0 = 0; k0 < IC; k0 += 64) {
        __syncthreads();
        #pragma unroll
        for (int i = 0; i < 4; ++i) {
            int G = t + i * 256;
            int row = G >> 3;
            int gsrc = (G & 7) ^ (row & 7);
            __builtin_amdgcn_global_load_lds(
                (gas_void*)&Ay[(size_t)(m0 + row) * IC + k0 + gsrc * 8],
                (las_void*)&a_lds[G * 8], 16, 0, 0);
            __builtin_amdgcn_global_load_lds(
                (gas_void*)&BT[(size_t)(n0 + row) * IC + k0 + gsrc * 8],
                (las_void*)&b_lds[G * 8], 16, 0, 0);
        }
        __syncthreads();
        #pragma unroll
        for (int ks = 0; ks < 2; ++ks) {
            bf16x8 af[4], bfr[4];
            int gc = ks * 4 + (l >> 4);
            #pragma unroll
            for (int mi = 0; mi < 4; ++mi) {
                int r = wr * 64 + mi * 16 + (l & 15);
                af[mi] = *(const bf16x8*)&a_lds[(r * 8 + (gc ^ (r & 7))) * 8];
            }
            #pragma unroll
            for (int ni = 0; ni < 4; ++ni) {
                int r = wc * 64 + ni * 16 + (l & 15);
                bfr[ni] = *(const bf16x8*)&b_lds[(r * 8 + (gc ^ (r & 7))) * 8];
            }
            #pragma unroll
            for (int mi = 0; mi < 4; ++mi)
                #pragma unroll
                for (int ni = 0; ni < 4; ++ni)
                    acc[mi][ni] = __builtin_amdgcn_mfma_f32_16x16x32_bf16(af[mi], bfr[ni], acc[mi][ni], 0, 0, 0);
        }
    }
    int nb = m0 >> 11;
    #pragma unroll
    for (int ni = 0; ni < 4; ++ni) {
        int c = n0 + wc * 64 + ni * 16 + (l & 15);
        float bv = bias[c];
        float sc = scaleshift[c], sh = scaleshift[512 + c];
        #pragma unroll
        for (int mi = 0; mi < 4; ++mi) {
            int li = (m0 & 2047) + wr * 64 + mi * 16 + (l >> 4) * 4;
            size_t base = (((size_t)nb * CC + c) << 11) + li;
            float4 a = *(const float4*)&Aorig[base];
            float4 o;
            o.x = fmaxf(a.x * sc + sh, 0.f) + acc[mi][ni][0] + bv;
            o.y = fmaxf(a.y * sc + sh, 0.f) + acc[mi][ni][1] + bv;
            o.z = fmaxf(a.z * sc + sh, 0.f) + acc[mi][ni][2] + bv;
            o.w = fmaxf(a.w * sc + sh, 0.f) + acc[mi][ni][3] + bv;
            *(float4*)&Out[base] = o;
        }
    }
}

// ---------------- flash attention: LDS double-buffered K/V, split QK chains ----------------
// Q low half (d 0..127) persistent in regs; high half streamed from L2 per iter so the
// QK^T 16-MFMA serial chain splits into two independent 8-chains within the reg budget.
__global__ __launch_bounds__(256, 2) void flash_attn32(
    const bf16* __restrict__ QB, const bf16* __restrict__ KB,
    const bf16* __restrict__ VB, bf16* __restrict__ part, float* __restrict__ ml)
{
    int bid = blockIdx.x;                   // 512 = 8 batch * 4 split * 16 qtile
    int nb = bid & 7;
    int split = (bid >> 3) & 3;
    int qt = bid >> 5;
    int t = threadIdx.x, l = t & 63, w = t >> 6;
    int h = l >> 5, ql = l & 31;
    int qrow = qt * 128 + w * 32 + ql;
    const bf16* Qblk = QB + (size_t)nb * BATCH_STRIDE + (size_t)(qt * 4 + w) * 8192;
    const bf16* Kb = KB + (size_t)nb * BATCH_STRIDE;
    const bf16* Vb = VB + (size_t)nb * BATCH_STRIDE;

    __shared__ bf16 k_lds[2][8192];
    __shared__ bf16 v_lds[2][8192];

    int kb0 = split * 16;

    auto stage = [&](int buf, int blk) {
        const bf16* kg = Kb + (size_t)blk * 8192;
        const bf16* vg = Vb + (size_t)blk * 8192;
        #pragma unroll
        for (int i = 0; i < 4; ++i) {
            int e0 = (t + i * 256) * 8;
            __builtin_amdgcn_global_load_lds((gas_void*)(kg + e0),
                                             (las_void*)&k_lds[buf][e0], 16, 0, 0);
            __builtin_amdgcn_global_load_lds((gas_void*)(vg + e0),
                                             (las_void*)&v_lds[buf][e0], 16, 0, 0);
        }
    };

    stage(0, kb0);

    // persistent Q: low half only (dc 0..7 -> d 0..127)
    bf16x8 qf[8];
    #pragma unroll
    for (int dc = 0; dc < 8; ++dc)
        qf[dc] = *(const bf16x8*)&Qblk[(dc * 2 + h) * 256 + ql * 8];

    f32x16 o[8] = {};
    float m = -__builtin_inff(), ell = 0.f;

    __syncthreads();

    int buf = 0;
    for (int it = 0; it < 16; ++it) {
        if (it < 15) stage(buf ^ 1, kb0 + it + 1);

        // stream Q high half (L2-hot; opaque ptr defeats LICM so regs stay transient)
        const bf16* qsrc = Qblk;
        asm("" : "+v"(qsrc));
        bf16x8 qh[8];
        #pragma unroll
        for (int j = 0; j < 8; ++j)
            qh[j] = *(const bf16x8*)&qsrc[((j + 8) * 2 + h) * 256 + ql * 8];

        // ---- QK^T: two independent 8-MFMA chains ----
        f32x16 s = {}, s2 = {};
        #pragma unroll
        for (int dc = 0; dc < 8; ++dc) {
            bf16x8 kf = *(const bf16x8*)&k_lds[buf][(dc * 2 + h) * 256 + ql * 8];
            s = __builtin_amdgcn_mfma_f32_32x32x16_bf16(kf, qf[dc], s, 0, 0, 0);
        }
        #pragma unroll
        for (int dc = 8; dc < 16; ++dc) {
            bf16x8 kf = *(const bf16x8*)&k_lds[buf][(dc * 2 + h) * 256 + ql * 8];
            s2 = __builtin_amdgcn_mfma_f32_32x32x16_bf16(kf, qh[dc - 8], s2, 0, 0, 0);
        }
        #pragma unroll
        for (int r = 0; r < 16; ++r) s[r] += s2[r];

        // ---- softmax (tree reductions, lane-local q) ----
        float a0 = fmaxf(fmaxf(s[0], s[1]), fmaxf(s[2], s[3]));
        float a1 = fmaxf(fmaxf(s[4], s[5]), fmaxf(s[6], s[7]));
        float a2 = fmaxf(fmaxf(s[8], s[9]), fmaxf(s[10], s[11]));
        float a3 = fmaxf(fmaxf(s[12], s[13]), fmaxf(s[14], s[15]));
        float tm = fmaxf(fmaxf(a0, a1), fmaxf(a2, a3));
        tm = fmaxf(tm, __shfl_xor(tm, 32));
        if (!__all(tm <= m + 8.f)) {         // defer-max (T13)
            float nm = fmaxf(m, tm);
            float fac = __expf(m - nm);
            m = nm;
            ell *= fac;
            #pragma unroll
            for (int c = 0; c < 8; ++c)
                #pragma unroll
                for (int r = 0; r < 16; ++r) o[c][r] *= fac;
        }
        #pragma unroll
        for (int r = 0; r < 16; ++r) s[r] = __expf(s[r] - m);
        float t0 = (s[0] + s[1]) + (s[2] + s[3]);
        float t1 = (s[4] + s[5]) + (s[6] + s[7]);
        float t2 = (s[8] + s[9]) + (s[10] + s[11]);
        float t3 = (s[12] + s[13]) + (s[14] + s[15]);
        float ts = (t0 + t1) + (t2 + t3);
        ell += ts + __shfl_xor(ts, 32);

        // ---- pack P -> PV B-operand fragments via permlane32_swap (T12) ----
        unsigned wd[8];
        #pragma unroll
        for (int j = 0; j < 8; ++j) wd[j] = packbf(s[2 * j], s[2 * j + 1]);
        plswap(wd[0], wd[2]);
        plswap(wd[1], wd[3]);
        plswap(wd[4], wd[6]);
        plswap(wd[5], wd[7]);
        u32x4 q0v = { wd[0], wd[1], wd[2], wd[3] };
        u32x4 q1v = { wd[4], wd[5], wd[6], wd[7] };
        bf16x8 pf0 = __builtin_bit_cast(bf16x8, q0v);
        bf16x8 pf1 = __builtin_bit_cast(bf16x8, q1v);

        // ---- PV ----
        #pragma unroll
        for (int c = 0; c < 8; ++c) {
            bf16x8 v0 = *(const bf16x8*)&v_lds[buf][(c * 4 + h) * 256 + ql * 8];
            bf16x8 v1 = *(const bf16x8*)&v_lds[buf][(c * 4 + 2 + h) * 256 + ql * 8];
            o[c] = __builtin_amdgcn_mfma_f32_32x32x16_bf16(v0, pf0, o[c], 0, 0, 0);
            o[c] = __builtin_amdgcn_mfma_f32_32x32x16_bf16(v1, pf1, o[c], 0, 0, 0);
        }

        __syncthreads();
        buf ^= 1;
    }

    size_t prow = (((size_t)split * NB + nb) << 11) + qrow;
    #pragma unroll
    for (int c = 0; c < 8; ++c)
        #pragma unroll
        for (int rq = 0; rq < 4; ++rq) {
            u32x2 u = { packbf(o[c][rq * 4 + 0], o[c][rq * 4 + 1]),
                        packbf(o[c][rq * 4 + 2], o[c][rq * 4 + 3]) };
            bf16x4 pv = __builtin_bit_cast(bf16x4, u);
            *(bf16x4*)&part[prow * IC + c * 32 + 8 * rq + 4 * h] = pv;
        }
    if (l < 32) {
        ml[prow * 2] = m;
        ml[prow * 2 + 1] = ell;
    }
}

// ---------------- combine split-KV partials -> Y [8][2048][256] bf16 ----------------
__global__ __launch_bounds__(256) void attn_combine(
    const bf16* __restrict__ part, const float* __restrict__ ml, bf16* __restrict__ Y)
{
    int t = threadIdx.x;
    int rowg = blockIdx.x * 8 + (t >> 5);
    int lane = t & 31;
    float m[NSPLIT], lv[NSPLIT];
    float M = -__builtin_inff();
    #pragma unroll
    for (int s = 0; s < NSPLIT; ++s) {
        m[s] = ml[((size_t)s * NLTOT + rowg) * 2];
        lv[s] = ml[((size_t)s * NLTOT + rowg) * 2 + 1];
        M = fmaxf(M, m[s]);
    }
    float L = 0.f, wgt[NSPLIT];
    #pragma unroll
    for (int s = 0; s < NSPLIT; ++s) {
        wgt[s] = __expf(m[s] - M);
        L += lv[s] * wgt[s];
    }
    float invL = 1.0f / L;
    float acc[8] = {};
    #pragma unroll
    for (int s = 0; s < NSPLIT; ++s) {
        bf16x8 v = *(const bf16x8*)&part[((size_t)s * NLTOT + rowg) * IC + lane * 8];
        #pragma unroll
        for (int e = 0; e < 8; ++e) acc[e] += wgt[s] * (float)v[e];
    }
    bf16 outv[8];
    #pragma unroll
    for (int e = 0; e < 8; ++e) outv[e] = f2bf(acc[e] * invL);
    *(bf16x8*)&Y[(size_t)rowg * IC + lane * 8] = *(bf16x8*)outv;
}

extern "C" void kernel_launch(void* const* d_in, const int* in_sizes, int n_in,
                              void* d_out, int out_size, void* d_ws, size_t ws_size,
                              hipStream_t stream) {
    const float* A       = (const float*)d_in[0];
    const float* B       = (const float*)d_in[1];
    const float* gamma   = (const float*)d_in[2];
    const float* beta    = (const float*)d_in[3];
    const float* theta_w = (const float*)d_in[4];
    const float* theta_b = (const float*)d_in[5];
    const float* phi_w   = (const float*)d_in[6];
    const float* phi_b   = (const float*)d_in[7];
    const float* g_w     = (const float*)d_in[8];
    const float* g_b     = (const float*)d_in[9];
    const float* W_w     = (const float*)d_in[10];
    const float* W_b     = (const float*)d_in[11];
    float* Out = (float*)d_out;

    char* ws = (char*)d_ws;
    float* scaleshift = (float*)(ws + oScale);
    bf16* wts    = (bf16*)(ws + oWT);
    bf16* WwT    = wts + 3 * 131072;
    bf16* An = (bf16*)(ws + oAn);
    bf16* Bn = (bf16*)(ws + oBn);
    bf16* qB = (bf16*)(ws + oQ);
    bf16* kB = (bf16*)(ws + oK);
    bf16* vB = (bf16*)(ws + oVT);
    bf16* y  = (bf16*)(ws + oY);
    bf16* part = (bf16*)(ws + oAn);     // 32 MB over An+Bn (dead after QKV gemms)
    float* ml  = (float*)(ws + oProj);  // 512 KB

    prep_and_stats<<<3072, 256, 0, stream>>>(theta_w, phi_w, g_w, W_w,
                                             A, B, gamma, beta, wts, scaleshift);
    bn_apply_transpose<<<4096, 256, 0, stream>>>(A, B, scaleshift, An, Bn);

    gemm_qkv<<<768, 256, 0, stream>>>(An, Bn, wts, theta_b, phi_b, g_b, qB, kB, vB);

    flash_attn32<<<128 * NSPLIT, 256, 0, stream>>>(qB, kB, vB, part, ml);
    attn_combine<<<2048, 256, 0, stream>>>(part, ml, y);

    gemm_w_fused<<<512, 256, 0, stream>>>(y, WwT, W_b, A, scaleshift, Out);
}

// Round 16
// 132.965 us; speedup vs baseline: 1.0357x; 1.0357x over previous
//
#include <hip/hip_runtime.h>

using bf16 = __bf16;
typedef __attribute__((ext_vector_type(8))) __bf16 bf16x8;
typedef __attribute__((ext_vector_type(4))) __bf16 bf16x4;
typedef __attribute__((ext_vector_type(4))) float f32x4;
typedef __attribute__((ext_vector_type(16))) float f32x16;
typedef __attribute__((ext_vector_type(4))) unsigned u32x4;
typedef __attribute__((ext_vector_type(2))) unsigned u32x2;

#define NB 8
#define CC 512
#define LL 2048
#define IC 256
#define NLTOT 16384
#define NSPLIT 4
#define BATCH_STRIDE 524288   // 2048*256 elements per batch for q/k/v blocked tensors

__device__ inline bf16 f2bf(float f) {
    unsigned u = __builtin_bit_cast(unsigned, f);
    unsigned r = (u + 0x7fff + ((u >> 16) & 1)) >> 16;
    return __builtin_bit_cast(bf16, (unsigned short)r);
}
__device__ inline unsigned packbf(float lo, float hi) {
    unsigned a = (unsigned)__builtin_bit_cast(unsigned short, f2bf(lo));
    unsigned b = (unsigned)__builtin_bit_cast(unsigned short, f2bf(hi));
    return (b << 16) | a;
}
// exchange: a[32..63] <-> b[0..31]  (pure VALU; distinct live operands -> distinct regs)
__device__ inline void plswap(unsigned& a, unsigned& b) {
    asm("v_permlane32_swap_b32 %0, %1" : "+v"(a), "+v"(b));
}

typedef const __attribute__((address_space(1))) void gas_void;
typedef __attribute__((address_space(3))) void las_void;

// ---------------- ws layout (bytes) ----------------
static constexpr size_t oScale = 0;                       // 8192 B
static constexpr size_t oWT    = 8192;                    // thetaT,phiT,gT,WwT bf16
static constexpr size_t oAn    = oWT + 4ull * 262144;     // 16 MB (reused: attn partials span An+Bn)
static constexpr size_t oBn    = oAn + 16777216ull;       // 16 MB
static constexpr size_t oQ     = oBn + 16777216ull;       // 8 MB (qB blocked)
static constexpr size_t oK     = oQ + 8388608ull;         // 8 MB (kB blocked)
static constexpr size_t oVT    = oK + 8388608ull;         // 8 MB (vB blocked)
static constexpr size_t oY     = oVT + 8388608ull;        // 8 MB
static constexpr size_t oProj  = oY + 8388608ull;         // reused: attn m/l only (512 KB)

// ---------------- weight prep + BN stats in one launch ----------------
// blocks 0..2047: weight transpose+cvt; blocks 2048..3071: BN stats
__global__ __launch_bounds__(256) void prep_and_stats(
    const float* __restrict__ theta_w, const float* __restrict__ phi_w,
    const float* __restrict__ g_w, const float* __restrict__ W_w,
    const float* __restrict__ A, const float* __restrict__ B,
    const float* __restrict__ gamma, const float* __restrict__ beta,
    bf16* __restrict__ wts, float* __restrict__ scaleshift)
{
    int bidx = blockIdx.x;
    int t = threadIdx.x;
    if (bidx < 2048) {
        int idx = bidx * 256 + t;
        int which = idx >> 17;
        int o = idx & 131071;
        float v;
        if (which < 3) {
            const float* W = which == 0 ? theta_w : (which == 1 ? phi_w : g_w);
            int ic = o >> 9, cc = o & 511;
            v = W[cc * IC + ic];
        } else {
            int cc = o >> 8, ic = o & 255;
            v = W_w[ic * CC + cc];
        }
        wts[(size_t)which * 131072 + o] = f2bf(v);
        return;
    }
    int bid = bidx - 2048;
    int tensor = bid >> 9, c = bid & 511;
    const float* X = tensor ? B : A;
    float s = 0.f, sq = 0.f;
    for (int n = 0; n < NB; ++n) {
        const float* row = &X[((size_t)(n * CC + c)) << 11];
        for (int j = t * 4; j < LL; j += 1024) {
            float4 v = *(const float4*)&row[j];
            s += v.x + v.y + v.z + v.w;
            sq += v.x * v.x + v.y * v.y + v.z * v.z + v.w * v.w;
        }
    }
    __shared__ float rs[256], rq[256];
    rs[t] = s; rq[t] = sq;
    __syncthreads();
    for (int step = 128; step > 0; step >>= 1) {
        if (t < step) { rs[t] += rs[t + step]; rq[t] += rq[t + step]; }
        __syncthreads();
    }
    if (t == 0) {
        float mean = rs[0] * (1.f / 16384.f);
        float var = rq[0] * (1.f / 16384.f) - mean * mean;
        float rsq = rsqrtf(var + 1e-5f);
        float sc = gamma[c] * rsq;
        scaleshift[tensor * 1024 + c] = sc;
        scaleshift[tensor * 1024 + 512 + c] = beta[c] - mean * sc;
    }
}

// ---------------- BN apply + ReLU + transpose -> bf16 [N,L,C], both tensors ----------------
__global__ __launch_bounds__(256) void bn_apply_transpose(
    const float* __restrict__ A, const float* __restrict__ B,
    const float* __restrict__ scaleshift,
    bf16* __restrict__ OutA, bf16* __restrict__ OutB)
{
    int bidx = blockIdx.x;                  // 4096 = 2 tensors * 2048
    int tensor = bidx >> 11;
    bidx &= 2047;
    const float* X = tensor ? B : A;
    const float* scale = scaleshift + tensor * 1024;
    const float* shift = scale + 512;
    bf16* Out = tensor ? OutB : OutA;
    int lt = bidx & 31, ct = (bidx >> 5) & 7, n = bidx >> 8;
    int c0 = ct * 64, l0 = lt * 64;
    __shared__ float tile[64][65];
    int t = threadIdx.x;
    #pragma unroll
    for (int i = 0; i < 4; ++i) {
        int r = i * 16 + (t >> 4);
        int c4 = (t & 15) * 4;
        float s = scale[c0 + r], sh = shift[c0 + r];
        float4 v = *(const float4*)&X[(((size_t)n * CC + c0 + r) << 11) + l0 + c4];
        tile[r][c4 + 0] = fmaxf(v.x * s + sh, 0.f);
        tile[r][c4 + 1] = fmaxf(v.y * s + sh, 0.f);
        tile[r][c4 + 2] = fmaxf(v.z * s + sh, 0.f);
        tile[r][c4 + 3] = fmaxf(v.w * s + sh, 0.f);
    }
    __syncthreads();
    #pragma unroll
    for (int i = 0; i < 2; ++i) {
        int lr = i * 32 + (t >> 3);
        int c8 = (t & 7) * 8;
        bf16 tmp[8];
        #pragma unroll
        for (int e = 0; e < 8; ++e) tmp[e] = f2bf(tile[c8 + e][lr]);
        *(bf16x8*)&Out[(((size_t)(n << 11)) + l0 + lr) * CC + c0 + c8] = *(bf16x8*)tmp;
    }
}

// ---------------- fused QKV GEMM: global_load_lds staging + XOR-swizzled LDS ----------------
__global__ __launch_bounds__(256) void gemm_qkv(
    const bf16* __restrict__ An, const bf16* __restrict__ Bn,
    const bf16* __restrict__ wts,
    const float* __restrict__ theta_b, const float* __restrict__ phi_b,
    const float* __restrict__ g_b,
    bf16* __restrict__ qB, bf16* __restrict__ kB, bf16* __restrict__ vB)
{
    int bid = blockIdx.x;
    int which = bid >> 8;
    int sub = bid & 255;
    const bf16* A  = (which == 1) ? Bn : An;
    const bf16* BT = wts + (size_t)which * 131072;
    const float* bias = which == 0 ? theta_b : (which == 1 ? phi_b : g_b);
    bf16* dst = which == 0 ? qB : (which == 1 ? kB : vB);

    int tn = sub & 1, tm = sub >> 1;
    int m0 = tm * 128, n0 = tn * 128;
    __shared__ bf16 a_lds[128 * 64];
    __shared__ bf16 b_lds[128 * 64];
    int t = threadIdx.x;
    int l = t & 63, w = t >> 6;
    int wr = w >> 1, wc = w & 1;
    f32x4 acc[4][4] = {};
    for (int k0 = 0; k0 < CC; k0 += 64) {
        __syncthreads();
        #pragma unroll
        for (int i = 0; i < 4; ++i) {
            int G = t + i * 256;             // 0..1023: row=G>>3, gcol=G&7
            int row = G >> 3;
            int gsrc = (G & 7) ^ (row & 7);  // inverse-swizzled source granule
            __builtin_amdgcn_global_load_lds(
                (gas_void*)&A[(size_t)(m0 + row) * CC + k0 + gsrc * 8],
                (las_void*)&a_lds[G * 8], 16, 0, 0);
            __builtin_amdgcn_global_load_lds(
                (gas_void*)&BT[(size_t)(n0 + row) * CC + k0 + gsrc * 8],
                (las_void*)&b_lds[G * 8], 16, 0, 0);
        }
        __syncthreads();                     // implicit vmcnt(0) drains the DMA
        #pragma unroll
        for (int ks = 0; ks < 2; ++ks) {
            bf16x8 af[4], bfr[4];
            int gc = ks * 4 + (l >> 4);
            #pragma unroll
            for (int mi = 0; mi < 4; ++mi) {
                int r = wr * 64 + mi * 16 + (l & 15);
                af[mi] = *(const bf16x8*)&a_lds[(r * 8 + (gc ^ (r & 7))) * 8];
            }
            #pragma unroll
            for (int ni = 0; ni < 4; ++ni) {
                int r = wc * 64 + ni * 16 + (l & 15);
                bfr[ni] = *(const bf16x8*)&b_lds[(r * 8 + (gc ^ (r & 7))) * 8];
            }
            #pragma unroll
            for (int mi = 0; mi < 4; ++mi)
                #pragma unroll
                for (int ni = 0; ni < 4; ++ni)
                    acc[mi][ni] = __builtin_amdgcn_mfma_f32_16x16x32_bf16(af[mi], bfr[ni], acc[mi][ni], 0, 0, 0);
        }
    }
    #pragma unroll
    for (int mi = 0; mi < 4; ++mi)
        #pragma unroll
        for (int ni = 0; ni < 4; ++ni) {
            int col = n0 + wc * 64 + ni * 16 + (l & 15);
            float bv = bias[col];
            int row0 = m0 + wr * 64 + mi * 16 + (l >> 4) * 4;
            int nb = row0 >> 11;
            int li0 = row0 & 2047;
            size_t base = (size_t)nb * BATCH_STRIDE + (size_t)(li0 >> 5) * 8192;
            if (which < 2) {
                size_t a0 = base + (col >> 3) * 256 + (li0 & 31) * 8 + (col & 7);
                #pragma unroll
                for (int r = 0; r < 4; ++r)
                    dst[a0 + r * 8] = f2bf(acc[mi][ni][r] + bv);
            } else {
                bf16 tmp[4];
                #pragma unroll
                for (int r = 0; r < 4; ++r) tmp[r] = f2bf(acc[mi][ni][r] + bv);
                int kvin = li0 & 31;
                int grp = ((col >> 5) << 2) | ((kvin >> 4) << 1) | ((kvin >> 3) & 1);
                *(bf16x4*)&dst[base + grp * 256 + (col & 31) * 8 + (kvin & 7)] = *(bf16x4*)tmp;
            }
        }
}

// ---------------- W-projection GEMM (same staging) fused with residual epilogue ----------------
__global__ __launch_bounds__(256) void gemm_w_fused(
    const bf16* __restrict__ Ay, const bf16* __restrict__ BT,
    const float* __restrict__ bias, const float* __restrict__ Aorig,
    const float* __restrict__ scaleshift, float* __restrict__ Out)
{
    int bid = blockIdx.x;                  // 512 = 128 m-tiles * 4 n-tiles
    int tn = bid & 3, tm = bid >> 2;
    int m0 = tm * 128, n0 = tn * 128;
    __shared__ bf16 a_lds[128 * 64];
    __shared__ bf16 b_lds[128 * 64];
    int t = threadIdx.x;
    int l = t & 63, w = t >> 6;
    int wr = w >> 1, wc = w & 1;
    f32x4 acc[4][4] = {};
    for (int k0 = 0; k0 < IC; k0 += 64) {
        __syncthreads();
        #pragma unroll
        for (int i = 0; i < 4; ++i) {
            int G = t + i * 256;
            int row = G >> 3;
            int gsrc = (G & 7) ^ (row & 7);
            __builtin_amdgcn_global_load_lds(
                (gas_void*)&Ay[(size_t)(m0 + row) * IC + k0 + gsrc * 8],
                (las_void*)&a_lds[G * 8], 16, 0, 0);
            __builtin_amdgcn_global_load_lds(
                (gas_void*)&BT[(size_t)(n0 + row) * IC + k0 + gsrc * 8],
                (las_void*)&b_lds[G * 8], 16, 0, 0);
        }
        __syncthreads();
        #pragma unroll
        for (int ks = 0; ks < 2; ++ks) {
            bf16x8 af[4], bfr[4];
            int gc = ks * 4 + (l >> 4);
            #pragma unroll
            for (int mi = 0; mi < 4; ++mi) {
                int r = wr * 64 + mi * 16 + (l & 15);
                af[mi] = *(const bf16x8*)&a_lds[(r * 8 + (gc ^ (r & 7))) * 8];
            }
            #pragma unroll
            for (int ni = 0; ni < 4; ++ni) {
                int r = wc * 64 + ni * 16 + (l & 15);
                bfr[ni] = *(const bf16x8*)&b_lds[(r * 8 + (gc ^ (r & 7))) * 8];
            }
            #pragma unroll
            for (int mi = 0; mi < 4; ++mi)
                #pragma unroll
                for (int ni = 0; ni < 4; ++ni)
                    acc[mi][ni] = __builtin_amdgcn_mfma_f32_16x16x32_bf16(af[mi], bfr[ni], acc[mi][ni], 0, 0, 0);
        }
    }
    int nb = m0 >> 11;
    #pragma unroll
    for (int ni = 0; ni < 4; ++ni) {
        int c = n0 + wc * 64 + ni * 16 + (l & 15);
        float bv = bias[c];
        float sc = scaleshift[c], sh = scaleshift[512 + c];
        #pragma unroll
        for (int mi = 0; mi < 4; ++mi) {
            int li = (m0 & 2047) + wr * 64 + mi * 16 + (l >> 4) * 4;
            size_t base = (((size_t)nb * CC + c) << 11) + li;
            float4 a = *(const float4*)&Aorig[base];
            float4 o;
            o.x = fmaxf(a.x * sc + sh, 0.f) + acc[mi][ni][0] + bv;
            o.y = fmaxf(a.y * sc + sh, 0.f) + acc[mi][ni][1] + bv;
            o.z = fmaxf(a.z * sc + sh, 0.f) + acc[mi][ni][2] + bv;
            o.w = fmaxf(a.w * sc + sh, 0.f) + acc[mi][ni][3] + bv;
            *(float4*)&Out[base] = o;
        }
    }
}

// ---------------- flash attention: LDS double-buffered K/V via global_load_lds ----------------
__global__ __launch_bounds__(256, 2) void flash_attn32(
    const bf16* __restrict__ QB, const bf16* __restrict__ KB,
    const bf16* __restrict__ VB, bf16* __restrict__ part, float* __restrict__ ml)
{
    int bid = blockIdx.x;                   // 512 = 8 batch * 4 split * 16 qtile
    int nb = bid & 7;
    int split = (bid >> 3) & 3;
    int qt = bid >> 5;
    int t = threadIdx.x, l = t & 63, w = t >> 6;
    int h = l >> 5, ql = l & 31;
    int qrow = qt * 128 + w * 32 + ql;
    const bf16* Qblk = QB + (size_t)nb * BATCH_STRIDE + (size_t)(qt * 4 + w) * 8192;
    const bf16* Kb = KB + (size_t)nb * BATCH_STRIDE;
    const bf16* Vb = VB + (size_t)nb * BATCH_STRIDE;

    __shared__ bf16 k_lds[2][8192];
    __shared__ bf16 v_lds[2][8192];

    int kb0 = split * 16;

    auto stage = [&](int buf, int blk) {
        const bf16* kg = Kb + (size_t)blk * 8192;
        const bf16* vg = Vb + (size_t)blk * 8192;
        #pragma unroll
        for (int i = 0; i < 4; ++i) {
            int e0 = (t + i * 256) * 8;
            __builtin_amdgcn_global_load_lds((gas_void*)(kg + e0),
                                             (las_void*)&k_lds[buf][e0], 16, 0, 0);
            __builtin_amdgcn_global_load_lds((gas_void*)(vg + e0),
                                             (las_void*)&v_lds[buf][e0], 16, 0, 0);
        }
    };

    stage(0, kb0);

    bf16x8 qf[16];
    #pragma unroll
    for (int dc = 0; dc < 16; ++dc)
        qf[dc] = *(const bf16x8*)&Qblk[(dc * 2 + h) * 256 + ql * 8];

    f32x16 o[8] = {};
    float m = -__builtin_inff(), ell = 0.f;

    __syncthreads();

    int buf = 0;
    for (int it = 0; it < 16; ++it) {
        if (it < 15) stage(buf ^ 1, kb0 + it + 1);

        // ---- QK^T ----
        f32x16 s = {};
        #pragma unroll
        for (int dc = 0; dc < 16; ++dc) {
            bf16x8 kf = *(const bf16x8*)&k_lds[buf][(dc * 2 + h) * 256 + ql * 8];
            s = __builtin_amdgcn_mfma_f32_32x32x16_bf16(kf, qf[dc], s, 0, 0, 0);
        }

        // ---- softmax (tree reductions, lane-local q) ----
        float a0 = fmaxf(fmaxf(s[0], s[1]), fmaxf(s[2], s[3]));
        float a1 = fmaxf(fmaxf(s[4], s[5]), fmaxf(s[6], s[7]));
        float a2 = fmaxf(fmaxf(s[8], s[9]), fmaxf(s[10], s[11]));
        float a3 = fmaxf(fmaxf(s[12], s[13]), fmaxf(s[14], s[15]));
        float tm = fmaxf(fmaxf(a0, a1), fmaxf(a2, a3));
        tm = fmaxf(tm, __shfl_xor(tm, 32));
        if (!__all(tm <= m + 8.f)) {         // defer-max (T13)
            float nm = fmaxf(m, tm);
            float fac = __expf(m - nm);
            m = nm;
            ell *= fac;
            #pragma unroll
            for (int c = 0; c < 8; ++c)
                #pragma unroll
                for (int r = 0; r < 16; ++r) o[c][r] *= fac;
        }
        #pragma unroll
        for (int r = 0; r < 16; ++r) s[r] = __expf(s[r] - m);
        float t0 = (s[0] + s[1]) + (s[2] + s[3]);
        float t1 = (s[4] + s[5]) + (s[6] + s[7]);
        float t2 = (s[8] + s[9]) + (s[10] + s[11]);
        float t3 = (s[12] + s[13]) + (s[14] + s[15]);
        float ts = (t0 + t1) + (t2 + t3);
        ell += ts + __shfl_xor(ts, 32);

        // ---- pack P -> PV B-operand fragments via permlane32_swap (T12) ----
        unsigned wd[8];
        #pragma unroll
        for (int j = 0; j < 8; ++j) wd[j] = packbf(s[2 * j], s[2 * j + 1]);
        plswap(wd[0], wd[2]);
        plswap(wd[1], wd[3]);
        plswap(wd[4], wd[6]);
        plswap(wd[5], wd[7]);
        u32x4 q0v = { wd[0], wd[1], wd[2], wd[3] };
        u32x4 q1v = { wd[4], wd[5], wd[6], wd[7] };
        bf16x8 pf0 = __builtin_bit_cast(bf16x8, q0v);
        bf16x8 pf1 = __builtin_bit_cast(bf16x8, q1v);

        // ---- PV ----
        #pragma unroll
        for (int c = 0; c < 8; ++c) {
            bf16x8 v0 = *(const bf16x8*)&v_lds[buf][(c * 4 + h) * 256 + ql * 8];
            bf16x8 v1 = *(const bf16x8*)&v_lds[buf][(c * 4 + 2 + h) * 256 + ql * 8];
            o[c] = __builtin_amdgcn_mfma_f32_32x32x16_bf16(v0, pf0, o[c], 0, 0, 0);
            o[c] = __builtin_amdgcn_mfma_f32_32x32x16_bf16(v1, pf1, o[c], 0, 0, 0);
        }

        __syncthreads();
        buf ^= 1;
    }

    size_t prow = (((size_t)split * NB + nb) << 11) + qrow;
    #pragma unroll
    for (int c = 0; c < 8; ++c)
        #pragma unroll
        for (int rq = 0; rq < 4; ++rq) {
            u32x2 u = { packbf(o[c][rq * 4 + 0], o[c][rq * 4 + 1]),
                        packbf(o[c][rq * 4 + 2], o[c][rq * 4 + 3]) };
            bf16x4 pv = __builtin_bit_cast(bf16x4, u);
            *(bf16x4*)&part[prow * IC + c * 32 + 8 * rq + 4 * h] = pv;
        }
    if (l < 32) {
        ml[prow * 2] = m;
        ml[prow * 2 + 1] = ell;
    }
}

// ---------------- combine split-KV partials -> Y [8][2048][256] bf16 ----------------
__global__ __launch_bounds__(256) void attn_combine(
    const bf16* __restrict__ part, const float* __restrict__ ml, bf16* __restrict__ Y)
{
    int t = threadIdx.x;
    int rowg = blockIdx.x * 8 + (t >> 5);
    int lane = t & 31;
    float m[NSPLIT], lv[NSPLIT];
    float M = -__builtin_inff();
    #pragma unroll
    for (int s = 0; s < NSPLIT; ++s) {
        m[s] = ml[((size_t)s * NLTOT + rowg) * 2];
        lv[s] = ml[((size_t)s * NLTOT + rowg) * 2 + 1];
        M = fmaxf(M, m[s]);
    }
    float L = 0.f, wgt[NSPLIT];
    #pragma unroll
    for (int s = 0; s < NSPLIT; ++s) {
        wgt[s] = __expf(m[s] - M);
        L += lv[s] * wgt[s];
    }
    float invL = 1.0f / L;
    float acc[8] = {};
    #pragma unroll
    for (int s = 0; s < NSPLIT; ++s) {
        bf16x8 v = *(const bf16x8*)&part[((size_t)s * NLTOT + rowg) * IC + lane * 8];
        #pragma unroll
        for (int e = 0; e < 8; ++e) acc[e] += wgt[s] * (float)v[e];
    }
    bf16 outv[8];
    #pragma unroll
    for (int e = 0; e < 8; ++e) outv[e] = f2bf(acc[e] * invL);
    *(bf16x8*)&Y[(size_t)rowg * IC + lane * 8] = *(bf16x8*)outv;
}

extern "C" void kernel_launch(void* const* d_in, const int* in_sizes, int n_in,
                              void* d_out, int out_size, void* d_ws, size_t ws_size,
                              hipStream_t stream) {
    const float* A       = (const float*)d_in[0];
    const float* B       = (const float*)d_in[1];
    const float* gamma   = (const float*)d_in[2];
    const float* beta    = (const float*)d_in[3];
    const float* theta_w = (const float*)d_in[4];
    const float* theta_b = (const float*)d_in[5];
    const float* phi_w   = (const float*)d_in[6];
    const float* phi_b   = (const float*)d_in[7];
    const float* g_w     = (const float*)d_in[8];
    const float* g_b     = (const float*)d_in[9];
    const float* W_w     = (const float*)d_in[10];
    const float* W_b     = (const float*)d_in[11];
    float* Out = (float*)d_out;

    char* ws = (char*)d_ws;
    float* scaleshift = (float*)(ws + oScale);
    bf16* wts    = (bf16*)(ws + oWT);
    bf16* WwT    = wts + 3 * 131072;
    bf16* An = (bf16*)(ws + oAn);
    bf16* Bn = (bf16*)(ws + oBn);
    bf16* qB = (bf16*)(ws + oQ);
    bf16* kB = (bf16*)(ws + oK);
    bf16* vB = (bf16*)(ws + oVT);
    bf16* y  = (bf16*)(ws + oY);
    bf16* part = (bf16*)(ws + oAn);     // 32 MB over An+Bn (dead after QKV gemms)
    float* ml  = (float*)(ws + oProj);  // 512 KB

    prep_and_stats<<<3072, 256, 0, stream>>>(theta_w, phi_w, g_w, W_w,
                                             A, B, gamma, beta, wts, scaleshift);
    bn_apply_transpose<<<4096, 256, 0, stream>>>(A, B, scaleshift, An, Bn);

    gemm_qkv<<<768, 256, 0, stream>>>(An, Bn, wts, theta_b, phi_b, g_b, qB, kB, vB);

    flash_attn32<<<128 * NSPLIT, 256, 0, stream>>>(qB, kB, vB, part, ml);
    attn_combine<<<2048, 256, 0, stream>>>(part, ml, y);

    gemm_w_fused<<<512, 256, 0, stream>>>(y, WwT, W_b, A, scaleshift, Out);
}